// Round 2
// baseline (347.576 us; speedup 1.0000x reference)
//
#include <hip/hip_runtime.h>
#include <math.h>

// Problem constants
#define NB 2
#define CC 256
#define HH 96
#define WW 96
#define GG 8
#define DD 32
#define NPOS 2304   // 48*48
#define NDELTA 95

// ---------------------------------------------------------------------------
// Kernel 1: pos tables (posx/posy: [95][256]) + wk_eff ([8][256])
// posx[δ][o] = (1/√2) Σ_f emb(δ)[f] · Wx[o][f], emb = [sin(2δ/1000^(f/64)), cos(...)]
// wk_eff[g][c] = Σ_d ab[g*32+d] · Wk[g*32+d][c]
// ---------------------------------------------------------------------------
__global__ __launch_bounds__(256) void pos_tables_kernel(
    const float* __restrict__ Wx, const float* __restrict__ Wy,
    const float* __restrict__ Wk, const float* __restrict__ ab,
    float* __restrict__ posx, float* __restrict__ posy, float* __restrict__ wkeff)
{
    int b = blockIdx.x;
    int t = threadIdx.x;
    if (b < NDELTA) {
        __shared__ float emb[128];
        float delta = (float)(b - 47);
        if (t < 64) {
            // dim = 1000^(t/64) ; ang = 2*delta/dim
            float dim_inv = exp2f(-(float)t * 0.15571537944784511f); // log2(1000)/64
            float ang = 2.0f * delta * dim_inv;
            emb[t]      = sinf(ang);
            emb[t + 64] = cosf(ang);
        }
        __syncthreads();
        float sx = 0.f, sy = 0.f;
        const float* wxr = Wx + t * 128;
        const float* wyr = Wy + t * 128;
        for (int f = 0; f < 128; ++f) {
            float e = emb[f];
            sx += e * wxr[f];
            sy += e * wyr[f];
        }
        const float inv_sqrt2 = 0.70710678118654752440f;
        posx[b * 256 + t] = sx * inv_sqrt2;
        posy[b * 256 + t] = sy * inv_sqrt2;
    } else {
        int g = b - NDELTA;   // 0..7
        float s = 0.f;
        for (int d = 0; d < 32; ++d)
            s += ab[g * 32 + d] * Wk[(g * 32 + d) * 256 + t];
        wkeff[g * 256 + t] = s;
    }
}

// ---------------------------------------------------------------------------
// Kernel 2: fused Q/V/e_key projection GEMM.
// C[o, n*2304+p] = Σ_c W(o,c) * xs(c,p),  xs = x[:, :, ::2, ::2]
// W rows: [0,256)=Wq, [256,512)=Wv, [512,520)=wk_eff
// ---------------------------------------------------------------------------
__global__ __launch_bounds__(256) void qkv_kernel(
    const float* __restrict__ x, const float* __restrict__ Wq,
    const float* __restrict__ Wv, const float* __restrict__ wkeff,
    float* __restrict__ qbuf, float* __restrict__ vbuf, float* __restrict__ ek)
{
    __shared__ float As[16][64];
    __shared__ float Bs[16][64];
    int mTile = blockIdx.x;   // 0..8 (520 rows -> 9 tiles)
    int nTile = blockIdx.y;   // 0..71
    int t = threadIdx.x;
    int tx = t & 15, ty = t >> 4;
    int colBase = nTile * 64;
    int n = colBase / NPOS;            // 2304 % 64 == 0 -> tile stays in one n
    int pBase = colBase - n * NPOS;

    // A loader: o = mTile*64 + (t&63), 4 c's at (t>>6)*4
    int lo = t & 63;
    int lc = (t >> 6) * 4;
    // B loader: c = t>>4, p chunk = (t&15)*4
    int bc = t >> 4;
    int bp = (t & 15) * 4;

    float acc[4][4] = {};

    for (int k0 = 0; k0 < 256; k0 += 16) {
        int o = mTile * 64 + lo;
        float4 w4 = make_float4(0.f, 0.f, 0.f, 0.f);
        if (o < 256)      w4 = *(const float4*)(Wq + o * 256 + k0 + lc);
        else if (o < 512) w4 = *(const float4*)(Wv + (o - 256) * 256 + k0 + lc);
        else if (o < 520) w4 = *(const float4*)(wkeff + (o - 512) * 256 + k0 + lc);
        As[lc + 0][lo] = w4.x;
        As[lc + 1][lo] = w4.y;
        As[lc + 2][lo] = w4.z;
        As[lc + 3][lo] = w4.w;

        int c = k0 + bc;
        const float* xrowbase = x + (n * 256 + c) * (96 * 96);
        float bv[4];
        #pragma unroll
        for (int jj = 0; jj < 4; ++jj) {
            int p = pBase + bp + jj;
            int i = p / 48, j = p - i * 48;
            bv[jj] = xrowbase[(2 * i) * 96 + 2 * j];
        }
        *(float4*)&Bs[bc][bp] = make_float4(bv[0], bv[1], bv[2], bv[3]);
        __syncthreads();

        #pragma unroll
        for (int kk = 0; kk < 16; ++kk) {
            float4 av = *(const float4*)&As[kk][ty * 4];
            float4 b4 = *(const float4*)&Bs[kk][tx * 4];
            float a[4] = {av.x, av.y, av.z, av.w};
            float bb[4] = {b4.x, b4.y, b4.z, b4.w};
            #pragma unroll
            for (int i = 0; i < 4; ++i)
                #pragma unroll
                for (int j = 0; j < 4; ++j)
                    acc[i][j] += a[i] * bb[j];
        }
        __syncthreads();
    }

    #pragma unroll
    for (int i = 0; i < 4; ++i) {
        int o = mTile * 64 + ty * 4 + i;
        if (o >= 520) continue;
        #pragma unroll
        for (int j = 0; j < 4; ++j) {
            int p = pBase + tx * 4 + j;
            float val = acc[i][j];
            if (o < 256) {
                int g = o >> 5, d = o & 31;
                qbuf[((n * 8 + g) * NPOS + p) * 32 + d] = val;
            } else if (o < 512) {
                int o2 = o - 256;
                int g = o2 >> 5, d = o2 & 31;
                vbuf[((n * 8 + g) * NPOS + p) * 32 + d] = val;
            } else {
                ek[(n * 8 + (o - 512)) * NPOS + p] = val;
            }
        }
    }
}

// ---------------------------------------------------------------------------
// Kernel 3: per-(n,g) A = exp(ek - max(ek)), in place.
// ---------------------------------------------------------------------------
__global__ __launch_bounds__(256) void softA_kernel(float* __restrict__ ekA)
{
    int ng = blockIdx.x;  // 0..15
    float* e = ekA + ng * NPOS;
    int t = threadIdx.x;
    __shared__ float red[256];
    float m = -1e30f;
    for (int k = t; k < NPOS; k += 256) m = fmaxf(m, e[k]);
    red[t] = m;
    __syncthreads();
    for (int s = 128; s > 0; s >>= 1) {
        if (t < s) red[t] = fmaxf(red[t], red[t + s]);
        __syncthreads();
    }
    m = red[0];
    for (int k = t; k < NPOS; k += 256) e[k] = __expf(e[k] - m);
}

// ---------------------------------------------------------------------------
// Kernel 4: attention. Block = 256 thr, one (n,g) + 32 queries.
// p[q][k] = A[k] * X[q][v] * Y[q][u]  (k = u*48+v), out[d][q] = Σ_k p·V[k][d] / l[q]
// ---------------------------------------------------------------------------
#define PPAD 99
__global__ __launch_bounds__(256) void attn_kernel(
    const float* __restrict__ qbuf, const float* __restrict__ vbuf,
    const float* __restrict__ ekA, const float* __restrict__ posx,
    const float* __restrict__ posy, float* __restrict__ oattn)
{
    __shared__ float Qs[32][32];
    __shared__ float Xs[32][49];
    __shared__ float Ys[32][49];
    __shared__ float Ps[32][PPAD];
    __shared__ float Vs[96 * 32];
    __shared__ float Ats[96];
    __shared__ float lred[32][8];
    __shared__ float red[1024];
    __shared__ float linv_s[32];

    int blk = blockIdx.x;
    int qt = blk % 72;
    int ng = blk / 72;           // n*8+g
    int n = ng >> 3, g = ng & 7;
    int qbase = qt * 32;
    int t = threadIdx.x;
    int qi8 = t >> 3;            // 0..31
    int l8 = t & 7;

    // load Q tile (32 queries x 32 d)
    {
        const float4* src = (const float4*)(qbuf + (ng * NPOS + qbase) * 32);
        ((float4*)&Qs[0][0])[t] = src[t];
    }
    __syncthreads();

    // e_x -> Xs, e_y -> Ys
    int qglob = qbase + qi8;
    int hq = qglob / 48, wq = qglob - hq * 48;
    const float* pxg = posx + g * 32;
    const float* pyg = posy + g * 32;
    float mx = -1e30f, my = -1e30f;
    #pragma unroll
    for (int j = 0; j < 6; ++j) {
        int v = l8 + 8 * j;
        const float* px = pxg + (wq - v + 47) * 256;
        const float* py = pyg + (hq - v + 47) * 256;
        float sx = 0.f, sy = 0.f;
        #pragma unroll
        for (int d = 0; d < 32; ++d) {
            float qd = Qs[qi8][d];
            sx += qd * px[d];
            sy += qd * py[d];
        }
        Xs[qi8][v] = sx;
        Ys[qi8][v] = sy;
        mx = fmaxf(mx, sx);
        my = fmaxf(my, sy);
    }
    lred[qi8][l8] = mx;
    __syncthreads();
    {
        float m8 = lred[qi8][0];
        #pragma unroll
        for (int j = 1; j < 8; ++j) m8 = fmaxf(m8, lred[qi8][j]);
        mx = m8;
    }
    __syncthreads();
    lred[qi8][l8] = my;
    __syncthreads();
    {
        float m8 = lred[qi8][0];
        #pragma unroll
        for (int j = 1; j < 8; ++j) m8 = fmaxf(m8, lred[qi8][j]);
        my = m8;
    }
    __syncthreads();
    #pragma unroll
    for (int j = 0; j < 6; ++j) {
        int v = l8 + 8 * j;
        Xs[qi8][v] = __expf(Xs[qi8][v] - mx);
        Ys[qi8][v] = __expf(Ys[qi8][v] - my);
    }

    float lacc = 0.f;
    // phase-B thread mapping: 4 k-slices (one per wave), 4q x 4d per thread
    int s4 = t >> 6;
    int c2 = t & 63;
    int d0 = (c2 & 7) * 4;
    int qi0 = (c2 >> 3) * 4;
    float acc[4][4] = {};

    const float4* vsrc_base = (const float4*)(vbuf + (size_t)ng * NPOS * 32);
    const float* Abase = ekA + ng * NPOS;

    for (int tile = 0; tile < 24; ++tile) {
        int k0 = tile * 96;
        __syncthreads();  // prev phase B done with Vs/Ps
        // stage V tile: 96*32 floats = 768 float4
        {
            const float4* src = vsrc_base + k0 * 8;
            float4* dst = (float4*)Vs;
            dst[t] = src[t];
            dst[t + 256] = src[t + 256];
            dst[t + 512] = src[t + 512];
        }
        if (t < 96) Ats[t] = Abase[k0 + t];
        __syncthreads();
        // phase A: build P tile
        int u0 = tile * 2;
        #pragma unroll
        for (int j = 0; j < 12; ++j) {
            int k = l8 + 8 * j;
            int v = (k < 48) ? k : (k - 48);
            int u = u0 + ((k >= 48) ? 1 : 0);
            float p = Ats[k] * Xs[qi8][v] * Ys[qi8][u];
            Ps[qi8][k] = p;
            lacc += p;
        }
        __syncthreads();
        // phase B: acc += P * V
        #pragma unroll
        for (int j = 0; j < 24; ++j) {
            int k = s4 + 4 * j;
            float4 vv = *(const float4*)&Vs[k * 32 + d0];
            #pragma unroll
            for (int qq = 0; qq < 4; ++qq) {
                float p = Ps[qi0 + qq][k];
                acc[qq][0] += p * vv.x;
                acc[qq][1] += p * vv.y;
                acc[qq][2] += p * vv.z;
                acc[qq][3] += p * vv.w;
            }
        }
    }

    // l reduction
    __syncthreads();
    lred[qi8][l8] = lacc;
    __syncthreads();
    if (t < 32) {
        float s = 0.f;
        #pragma unroll
        for (int j = 0; j < 8; ++j) s += lred[t][j];
        linv_s[t] = 1.0f / s;
    }
    // cross-slice acc reduction into red[q*32+d]
    for (int s = 0; s < 4; ++s) {
        if (s4 == s) {
            #pragma unroll
            for (int qq = 0; qq < 4; ++qq)
                #pragma unroll
                for (int dd = 0; dd < 4; ++dd) {
                    int o = (qi0 + qq) * 32 + d0 + dd;
                    if (s == 0) red[o] = acc[qq][dd];
                    else        red[o] += acc[qq][dd];
                }
        }
        __syncthreads();
    }
    // write out: oattn[n][g*32+d][qbase+qi]
    #pragma unroll
    for (int r = 0; r < 4; ++r) {
        int o = t * 4 + r;
        int qi = o >> 5, d = o & 31;
        float val = red[o] * linv_s[qi];
        oattn[((size_t)(n * 256 + g * 32 + d)) * NPOS + qbase + qi] = val;
    }
}

// ---------------------------------------------------------------------------
// Kernel 5: output projection GEMM: proj[n][o][p] = bp[o] + Σ_c Wp[o][c]·oattn[n][c][p]
// ---------------------------------------------------------------------------
__global__ __launch_bounds__(256) void proj_kernel(
    const float* __restrict__ oattn, const float* __restrict__ Wp,
    const float* __restrict__ bpv, float* __restrict__ proj)
{
    __shared__ float As[16][64];
    __shared__ float Bs[16][64];
    int mTile = blockIdx.x;   // 0..3
    int nTile = blockIdx.y;   // 0..71
    int t = threadIdx.x;
    int tx = t & 15, ty = t >> 4;
    int colBase = nTile * 64;
    int n = colBase / NPOS;
    int pBase = colBase - n * NPOS;

    int lo = t & 63;
    int lc = (t >> 6) * 4;
    int bc = t >> 4;
    int bp = (t & 15) * 4;

    float acc[4][4] = {};

    for (int k0 = 0; k0 < 256; k0 += 16) {
        int o = mTile * 64 + lo;
        float4 w4 = *(const float4*)(Wp + o * 256 + k0 + lc);
        As[lc + 0][lo] = w4.x;
        As[lc + 1][lo] = w4.y;
        As[lc + 2][lo] = w4.z;
        As[lc + 3][lo] = w4.w;
        int c = k0 + bc;
        *(float4*)&Bs[bc][bp] =
            *(const float4*)(oattn + ((size_t)(n * 256 + c)) * NPOS + pBase + bp);
        __syncthreads();
        #pragma unroll
        for (int kk = 0; kk < 16; ++kk) {
            float4 av = *(const float4*)&As[kk][ty * 4];
            float4 b4 = *(const float4*)&Bs[kk][tx * 4];
            float a[4] = {av.x, av.y, av.z, av.w};
            float bb[4] = {b4.x, b4.y, b4.z, b4.w};
            #pragma unroll
            for (int i = 0; i < 4; ++i)
                #pragma unroll
                for (int j = 0; j < 4; ++j)
                    acc[i][j] += a[i] * bb[j];
        }
        __syncthreads();
    }

    #pragma unroll
    for (int i = 0; i < 4; ++i) {
        int o = mTile * 64 + ty * 4 + i;
        float bias = bpv[o];
        #pragma unroll
        for (int j = 0; j < 4; ++j) {
            int p = pBase + tx * 4 + j;
            proj[((size_t)(n * 256 + o)) * NPOS + p] = acc[i][j] + bias;
        }
    }
}

// ---------------------------------------------------------------------------
// Kernel 6: bilinear 48->96 upsample (half-pixel, edge-renormalized == clamp)
// + residual: out = gamma*resized + x
// ---------------------------------------------------------------------------
__global__ __launch_bounds__(256) void resize_kernel(
    const float* __restrict__ proj, const float* __restrict__ x,
    const float* __restrict__ gamma, float* __restrict__ out)
{
    int idx = blockIdx.x * 256 + threadIdx.x;   // < 2*256*96*96
    int J = idx % 96;
    int tmp = idx / 96;
    int I = tmp % 96;
    int nc = tmp / 96;

    int jr = I >> 1;
    int r0, r1; float w0, w1;
    if ((I & 1) == 0) { r0 = (jr > 0) ? jr - 1 : 0; r1 = jr; w0 = 0.25f; w1 = 0.75f; }
    else              { r0 = jr; r1 = (jr < 47) ? jr + 1 : 47; w0 = 0.75f; w1 = 0.25f; }
    int jc = J >> 1;
    int c0, c1; float u0, u1;
    if ((J & 1) == 0) { c0 = (jc > 0) ? jc - 1 : 0; c1 = jc; u0 = 0.25f; u1 = 0.75f; }
    else              { c0 = jc; c1 = (jc < 47) ? jc + 1 : 47; u0 = 0.75f; u1 = 0.25f; }

    const float* P = proj + (size_t)nc * NPOS;
    float v = w0 * (u0 * P[r0 * 48 + c0] + u1 * P[r0 * 48 + c1]) +
              w1 * (u0 * P[r1 * 48 + c0] + u1 * P[r1 * 48 + c1]);
    out[idx] = gamma[0] * v + x[idx];
}

// ---------------------------------------------------------------------------
extern "C" void kernel_launch(void* const* d_in, const int* in_sizes, int n_in,
                              void* d_out, int out_size, void* d_ws, size_t ws_size,
                              hipStream_t stream)
{
    const float* x     = (const float*)d_in[0];
    const float* Wq    = (const float*)d_in[1];
    const float* Wk    = (const float*)d_in[2];
    const float* Wv    = (const float*)d_in[3];
    const float* Wx    = (const float*)d_in[4];
    const float* Wy    = (const float*)d_in[5];
    const float* ab    = (const float*)d_in[6];
    const float* Wp    = (const float*)d_in[7];
    const float* bp    = (const float*)d_in[8];
    const float* gamma = (const float*)d_in[9];
    float* out = (float*)d_out;

    float* ws = (float*)d_ws;
    float* posx  = ws;                               // 95*256
    float* posy  = posx + 95 * 256;                  // 95*256
    float* wkeff = posy + 95 * 256;                  // 8*256
    float* qbuf  = wkeff + 8 * 256;                  // 2*8*2304*32
    float* vbuf  = qbuf + 2 * 8 * NPOS * 32;         // 2*8*2304*32
    float* ekA   = vbuf + 2 * 8 * NPOS * 32;         // 2*8*2304
    float* oattn = ekA + 2 * 8 * NPOS;               // 2*256*2304
    float* proj  = oattn + 2 * 256 * NPOS;           // 2*256*2304

    hipLaunchKernelGGL(pos_tables_kernel, dim3(103), dim3(256), 0, stream,
                       Wx, Wy, Wk, ab, posx, posy, wkeff);
    hipLaunchKernelGGL(qkv_kernel, dim3(9, 72), dim3(256), 0, stream,
                       x, Wq, Wv, wkeff, qbuf, vbuf, ekA);
    hipLaunchKernelGGL(softA_kernel, dim3(16), dim3(256), 0, stream, ekA);
    hipLaunchKernelGGL(attn_kernel, dim3(1152), dim3(256), 0, stream,
                       qbuf, vbuf, ekA, posx, posy, oattn);
    hipLaunchKernelGGL(proj_kernel, dim3(4, 72), dim3(256), 0, stream,
                       oattn, Wp, bp, proj);
    hipLaunchKernelGGL(resize_kernel, dim3((2 * 256 * 96 * 96) / 256), dim3(256), 0, stream,
                       proj, x, gamma, out);
}

// Round 3
// 225.343 us; speedup vs baseline: 1.5424x; 1.5424x over previous
//
#include <hip/hip_runtime.h>
#include <math.h>

// Problem constants
#define NB 2
#define CC 256
#define NPOS 2304   // 48*48
#define NDELTA 95

typedef __attribute__((ext_vector_type(8))) short short8;
typedef __attribute__((ext_vector_type(4))) float floatx4;

__device__ inline unsigned short f2bf(float x) {
    unsigned int u = __float_as_uint(x);
    u = (u + 0x7FFFu + ((u >> 16) & 1u)) >> 16;
    return (unsigned short)u;
}
__device__ inline float bf2f(unsigned short h) {
    return __uint_as_float(((unsigned int)h) << 16);
}
__device__ inline unsigned int pk2(float a, float b) {
    return (unsigned int)f2bf(a) | ((unsigned int)f2bf(b) << 16);
}

// ---------------------------------------------------------------------------
// Kernel 1: pos tables (posx/posy: [95][256]) + wk_eff ([8][256])
// ---------------------------------------------------------------------------
__global__ __launch_bounds__(256) void pos_tables_kernel(
    const float* __restrict__ Wx, const float* __restrict__ Wy,
    const float* __restrict__ Wk, const float* __restrict__ ab,
    float* __restrict__ posx, float* __restrict__ posy, float* __restrict__ wkeff)
{
    int b = blockIdx.x;
    int t = threadIdx.x;
    if (b < NDELTA) {
        __shared__ float emb[128];
        float delta = (float)(b - 47);
        if (t < 64) {
            float dim_inv = exp2f(-(float)t * 0.15571537944784511f); // log2(1000)/64
            float ang = 2.0f * delta * dim_inv;
            emb[t]      = sinf(ang);
            emb[t + 64] = cosf(ang);
        }
        __syncthreads();
        float sx = 0.f, sy = 0.f;
        const float* wxr = Wx + t * 128;
        const float* wyr = Wy + t * 128;
        for (int f = 0; f < 128; ++f) {
            float e = emb[f];
            sx += e * wxr[f];
            sy += e * wyr[f];
        }
        const float inv_sqrt2 = 0.70710678118654752440f;
        posx[b * 256 + t] = sx * inv_sqrt2;
        posy[b * 256 + t] = sy * inv_sqrt2;
    } else {
        int g = b - NDELTA;
        float s = 0.f;
        for (int d = 0; d < 32; ++d)
            s += ab[g * 32 + d] * Wk[(g * 32 + d) * 256 + t];
        wkeff[g * 256 + t] = s;
    }
}

// ---------------------------------------------------------------------------
// Kernel 2: fused Q/V/e_key projection GEMM.
// qbuf layout: [ng][p][32d]   vbuf layout: [n][256ch][p]   ek: [ng][p]
// ---------------------------------------------------------------------------
__global__ __launch_bounds__(256) void qkv_kernel(
    const float* __restrict__ x, const float* __restrict__ Wq,
    const float* __restrict__ Wv, const float* __restrict__ wkeff,
    float* __restrict__ qbuf, float* __restrict__ vbuf, float* __restrict__ ek)
{
    __shared__ float As[16][64];
    __shared__ float Bs[16][64];
    int mTile = blockIdx.x;   // 0..8
    int nTile = blockIdx.y;   // 0..71
    int t = threadIdx.x;
    int tx = t & 15, ty = t >> 4;
    int colBase = nTile * 64;
    int n = colBase / NPOS;
    int pBase = colBase - n * NPOS;

    int lo = t & 63;
    int lc = (t >> 6) * 4;
    int bc = t >> 4;
    int bp = (t & 15) * 4;

    float acc[4][4] = {};

    for (int k0 = 0; k0 < 256; k0 += 16) {
        int o = mTile * 64 + lo;
        float4 w4 = make_float4(0.f, 0.f, 0.f, 0.f);
        if (o < 256)      w4 = *(const float4*)(Wq + o * 256 + k0 + lc);
        else if (o < 512) w4 = *(const float4*)(Wv + (o - 256) * 256 + k0 + lc);
        else if (o < 520) w4 = *(const float4*)(wkeff + (o - 512) * 256 + k0 + lc);
        As[lc + 0][lo] = w4.x;
        As[lc + 1][lo] = w4.y;
        As[lc + 2][lo] = w4.z;
        As[lc + 3][lo] = w4.w;

        int c = k0 + bc;
        const float* xrowbase = x + (n * 256 + c) * (96 * 96);
        float bv[4];
        #pragma unroll
        for (int jj = 0; jj < 4; ++jj) {
            int p = pBase + bp + jj;
            int i = p / 48, j = p - i * 48;
            bv[jj] = xrowbase[(2 * i) * 96 + 2 * j];
        }
        *(float4*)&Bs[bc][bp] = make_float4(bv[0], bv[1], bv[2], bv[3]);
        __syncthreads();

        #pragma unroll
        for (int kk = 0; kk < 16; ++kk) {
            float4 av = *(const float4*)&As[kk][ty * 4];
            float4 b4 = *(const float4*)&Bs[kk][tx * 4];
            float a[4] = {av.x, av.y, av.z, av.w};
            float bb[4] = {b4.x, b4.y, b4.z, b4.w};
            #pragma unroll
            for (int i = 0; i < 4; ++i)
                #pragma unroll
                for (int j = 0; j < 4; ++j)
                    acc[i][j] += a[i] * bb[j];
        }
        __syncthreads();
    }

    #pragma unroll
    for (int i = 0; i < 4; ++i) {
        int o = mTile * 64 + ty * 4 + i;
        if (o >= 520) continue;
        int p0 = pBase + tx * 4;
        if (o < 256) {
            int g = o >> 5, d = o & 31;
            #pragma unroll
            for (int j = 0; j < 4; ++j)
                qbuf[((size_t)(n * 8 + g) * NPOS + p0 + j) * 32 + d] = acc[i][j];
        } else if (o < 512) {
            int o2 = o - 256;
            *(float4*)(vbuf + (size_t)(n * 256 + o2) * NPOS + p0) =
                make_float4(acc[i][0], acc[i][1], acc[i][2], acc[i][3]);
        } else {
            *(float4*)(ek + (size_t)(n * 8 + (o - 512)) * NPOS + p0) =
                make_float4(acc[i][0], acc[i][1], acc[i][2], acc[i][3]);
        }
    }
}

// ---------------------------------------------------------------------------
// Kernel 3: per-(n,g) A = exp(ek - max(ek)), in place.
// ---------------------------------------------------------------------------
__global__ __launch_bounds__(256) void softA_kernel(float* __restrict__ ekA)
{
    int ng = blockIdx.x;
    float* e = ekA + (size_t)ng * NPOS;
    int t = threadIdx.x;
    __shared__ float red[256];
    float m = -1e30f;
    for (int k = t; k < NPOS; k += 256) m = fmaxf(m, e[k]);
    red[t] = m;
    __syncthreads();
    for (int s = 128; s > 0; s >>= 1) {
        if (t < s) red[t] = fmaxf(red[t], red[t + s]);
        __syncthreads();
    }
    m = red[0];
    for (int k = t; k < NPOS; k += 256) e[k] = __expf(e[k] - m);
}

// ---------------------------------------------------------------------------
// Kernel 4: attention via bf16 MFMA.
// Block = 256 thr (4 waves), Q-tile 64, k-tile 96.
// P'[q,k] = X[q,v]*Y[q,u]  (bf16, fragment order);  V̂[d,k]=A[k]*V[d,k] bf16,
// extra col d=32: V̂=A[k] -> row-sum l[q] from the same MFMA chain.
// ---------------------------------------------------------------------------
__global__ __launch_bounds__(256, 3) void attn_kernel(
    const float* __restrict__ qbuf, const float* __restrict__ vbuf,
    const float* __restrict__ ekA, const float* __restrict__ posx,
    const float* __restrict__ posy, float* __restrict__ oattn)
{
    __shared__ __align__(16) unsigned short P2[768 * 8];   // 12288 B, A-frag order
    __shared__ __align__(16) unsigned short Vt[576 * 8];   //  9216 B, B-frag order
    __shared__ unsigned short Xs[64 * 50];                 //  6400 B
    __shared__ unsigned short Ys[64 * 50];                 //  6400 B
    __shared__ __align__(16) unsigned short Pxs[95 * 40];  //  7600 B (bf16 pos, stride 40)
    __shared__ __align__(16) unsigned short Pys[95 * 40];  //  7600 B
    __shared__ float linv_s[64];

    int blk = blockIdx.x;
    int qt = blk % 36;
    int ng = blk / 36;
    int nb = ng >> 3, g = ng & 7;
    int qbase = qt * 64;
    int t = threadIdx.x;
    int m = t >> 6;     // wave id = q-group for MFMA
    int L = t & 63;

    // ---- stage pos tables as bf16 ----
    for (int s = t; s < 95 * 8; s += 256) {
        int row = s >> 3, c4 = (s & 7) * 4;
        float4 v = *(const float4*)(posx + row * 256 + g * 32 + c4);
        *(uint2*)&Pxs[row * 40 + c4] = make_uint2(pk2(v.x, v.y), pk2(v.z, v.w));
        float4 w = *(const float4*)(posy + row * 256 + g * 32 + c4);
        *(uint2*)&Pys[row * 40 + c4] = make_uint2(pk2(w.x, w.y), pk2(w.z, w.w));
    }
    __syncthreads();

    // ---- e_x / e_y phase: X = exp(q·posx), Y = exp(q·posy), no shift ----
    {
        int qlo = L >> 3, rlo = L & 7;
        for (int pass = 0; pass < 2; ++pass) {
            int oct = pass * 4 + m;           // q-octet 0..7
            int q = oct * 8 + qlo;
            int qglob = qbase + q;
            int base8 = qbase + oct * 8;
            int hq0 = base8 / 48;
            int sq0 = base8 - hq0 * 48;       // in {0,8,...,40}: no wrap in octet
            int wq = sq0 + qlo;
            float Qr[32];
            const float* qsrc = qbuf + ((size_t)ng * NPOS + qglob) * 32;
            #pragma unroll
            for (int j = 0; j < 8; ++j) {
                float4 qv = *(const float4*)(qsrc + j * 4);
                Qr[j * 4 + 0] = qv.x; Qr[j * 4 + 1] = qv.y;
                Qr[j * 4 + 2] = qv.z; Qr[j * 4 + 3] = qv.w;
            }
            // X: rows [sq0, sq0+55)
            #pragma unroll
            for (int rb = 0; rb < 7; ++rb) {
                int row = sq0 + rb * 8 + rlo;
                if (row < 95) {
                    float s = 0.f;
                    #pragma unroll
                    for (int ch = 0; ch < 4; ++ch) {
                        uint4 pkv = *(const uint4*)&Pxs[row * 40 + ch * 8];
                        s += bf2f((unsigned short)(pkv.x & 0xffffu)) * Qr[ch*8+0]
                           + bf2f((unsigned short)(pkv.x >> 16))     * Qr[ch*8+1]
                           + bf2f((unsigned short)(pkv.y & 0xffffu)) * Qr[ch*8+2]
                           + bf2f((unsigned short)(pkv.y >> 16))     * Qr[ch*8+3]
                           + bf2f((unsigned short)(pkv.z & 0xffffu)) * Qr[ch*8+4]
                           + bf2f((unsigned short)(pkv.z >> 16))     * Qr[ch*8+5]
                           + bf2f((unsigned short)(pkv.w & 0xffffu)) * Qr[ch*8+6]
                           + bf2f((unsigned short)(pkv.w >> 16))     * Qr[ch*8+7];
                    }
                    int v = wq - row + 47;
                    if (v >= 0 && v < 48)
                        Xs[q * 50 + v] = f2bf(__expf(s));
                }
            }
            // Y: rows [hq0, hq0+55)
            #pragma unroll
            for (int rb = 0; rb < 7; ++rb) {
                int row = hq0 + rb * 8 + rlo;
                if (row < 95) {
                    float s = 0.f;
                    #pragma unroll
                    for (int ch = 0; ch < 4; ++ch) {
                        uint4 pkv = *(const uint4*)&Pys[row * 40 + ch * 8];
                        s += bf2f((unsigned short)(pkv.x & 0xffffu)) * Qr[ch*8+0]
                           + bf2f((unsigned short)(pkv.x >> 16))     * Qr[ch*8+1]
                           + bf2f((unsigned short)(pkv.y & 0xffffu)) * Qr[ch*8+2]
                           + bf2f((unsigned short)(pkv.y >> 16))     * Qr[ch*8+3]
                           + bf2f((unsigned short)(pkv.z & 0xffffu)) * Qr[ch*8+4]
                           + bf2f((unsigned short)(pkv.z >> 16))     * Qr[ch*8+5]
                           + bf2f((unsigned short)(pkv.w & 0xffffu)) * Qr[ch*8+6]
                           + bf2f((unsigned short)(pkv.w >> 16))     * Qr[ch*8+7];
                    }
                    int u = hq0 - row + 47;
                    if (u >= 0 && u < 48)
                        Ys[q * 50 + u] = f2bf(__expf(s));
                }
            }
        }
    }
    __syncthreads();

    // ---- preload this thread's 24 X values (same v-set for every k-tile) ----
    int qp = m * 16 + (L & 15);
    int o = L >> 4;
    float Xr[24];
    #pragma unroll
    for (int c = 0; c < 3; ++c)
        #pragma unroll
        for (int j = 0; j < 8; ++j) {
            int k = c * 32 + o * 8 + j;
            int v = (k < 48) ? k : k - 48;
            Xr[c * 8 + j] = bf2f(Xs[qp * 50 + v]);
        }

    floatx4 acc0 = {0.f, 0.f, 0.f, 0.f};
    floatx4 acc1 = {0.f, 0.f, 0.f, 0.f};
    floatx4 acc2 = {0.f, 0.f, 0.f, 0.f};

    const float* vb = vbuf + (size_t)ng * 32 * NPOS;   // [32 d][2304 k]
    const float* Ab = ekA + (size_t)ng * NPOS;

    for (int tile = 0; tile < 24; ++tile) {
        int k0 = tile * 96;
        __syncthreads();   // prior MFMA done reading P2/Vt

        // stage V̂ = A*V in B-frag order (+ l-column group nn==2)
        for (int s = t; s < 576; s += 256) {
            int grp = s >> 6;          // c*3+nn
            int Ls = s & 63;
            int cc = grp / 3;
            int nn = grp - cc * 3;
            int koct = cc * 32 + ((Ls >> 4) << 3);
            uint4 w = make_uint4(0u, 0u, 0u, 0u);
            if (nn < 2) {
                int d = nn * 16 + (Ls & 15);
                const float* vp = vb + (size_t)d * NPOS + k0 + koct;
                const float* ap = Ab + k0 + koct;
                float4 v0 = *(const float4*)vp;
                float4 v1 = *(const float4*)(vp + 4);
                float4 a0 = *(const float4*)ap;
                float4 a1 = *(const float4*)(ap + 4);
                w.x = pk2(v0.x * a0.x, v0.y * a0.y);
                w.y = pk2(v0.z * a0.z, v0.w * a0.w);
                w.z = pk2(v1.x * a1.x, v1.y * a1.y);
                w.w = pk2(v1.z * a1.z, v1.w * a1.w);
            } else if ((Ls & 15) == 0) {
                const float* ap = Ab + k0 + koct;
                float4 a0 = *(const float4*)ap;
                float4 a1 = *(const float4*)(ap + 4);
                w.x = pk2(a0.x, a0.y);
                w.y = pk2(a0.z, a0.w);
                w.z = pk2(a1.x, a1.y);
                w.w = pk2(a1.z, a1.w);
            }
            *(uint4*)&Vt[s * 8] = w;
        }

        // build P' tile in A-frag order
        {
            float Y0 = bf2f(Ys[qp * 50 + tile * 2]);
            float Y1 = bf2f(Ys[qp * 50 + tile * 2 + 1]);
            float Yc[3];
            Yc[0] = Y0;
            Yc[1] = (o < 2) ? Y0 : Y1;
            Yc[2] = Y1;
            #pragma unroll
            for (int c = 0; c < 3; ++c) {
                float yv = Yc[c];
                uint4 w;
                w.x = pk2(Xr[c*8+0] * yv, Xr[c*8+1] * yv);
                w.y = pk2(Xr[c*8+2] * yv, Xr[c*8+3] * yv);
                w.z = pk2(Xr[c*8+4] * yv, Xr[c*8+5] * yv);
                w.w = pk2(Xr[c*8+6] * yv, Xr[c*8+7] * yv);
                *(uint4*)&P2[((c * 4 + m) * 64 + L) * 8] = w;
            }
        }
        __syncthreads();   // writes visible

        // MFMA: per wave, q-group m × {d0-15, d16-31, l-col}
        #pragma unroll
        for (int c = 0; c < 3; ++c) {
            short8 a  = *(const short8*)&P2[((c * 4 + m) * 64 + L) * 8];
            short8 b0 = *(const short8*)&Vt[((c * 3 + 0) * 64 + L) * 8];
            short8 b1 = *(const short8*)&Vt[((c * 3 + 1) * 64 + L) * 8];
            short8 b2 = *(const short8*)&Vt[((c * 3 + 2) * 64 + L) * 8];
            acc0 = __builtin_amdgcn_mfma_f32_16x16x32_bf16(a, b0, acc0, 0, 0, 0);
            acc1 = __builtin_amdgcn_mfma_f32_16x16x32_bf16(a, b1, acc1, 0, 0, 0);
            acc2 = __builtin_amdgcn_mfma_f32_16x16x32_bf16(a, b2, acc2, 0, 0, 0);
        }
    }

    // ---- epilogue: l from acc2 col 0, normalize, store ----
    if ((L & 15) == 0) {
        int qc = m * 16 + (L >> 4) * 4;
        #pragma unroll
        for (int r = 0; r < 4; ++r)
            linv_s[qc + r] = 1.0f / acc2[r];
    }
    __syncthreads();
    {
        int qc = m * 16 + (L >> 4) * 4;
        float4 li = *(const float4*)&linv_s[qc];
        int d0 = L & 15;
        float* r0 = oattn + ((size_t)(nb * 256 + g * 32 + d0)) * NPOS + qbase + qc;
        *(float4*)r0 = make_float4(acc0[0] * li.x, acc0[1] * li.y,
                                   acc0[2] * li.z, acc0[3] * li.w);
        float* r1 = oattn + ((size_t)(nb * 256 + g * 32 + 16 + d0)) * NPOS + qbase + qc;
        *(float4*)r1 = make_float4(acc1[0] * li.x, acc1[1] * li.y,
                                   acc1[2] * li.z, acc1[3] * li.w);
    }
}

// ---------------------------------------------------------------------------
// Kernel 5: output projection GEMM
// ---------------------------------------------------------------------------
__global__ __launch_bounds__(256) void proj_kernel(
    const float* __restrict__ oattn, const float* __restrict__ Wp,
    const float* __restrict__ bpv, float* __restrict__ proj)
{
    __shared__ float As[16][64];
    __shared__ float Bs[16][64];
    int mTile = blockIdx.x;   // 0..3
    int nTile = blockIdx.y;   // 0..71
    int t = threadIdx.x;
    int tx = t & 15, ty = t >> 4;
    int colBase = nTile * 64;
    int n = colBase / NPOS;
    int pBase = colBase - n * NPOS;

    int lo = t & 63;
    int lc = (t >> 6) * 4;
    int bc = t >> 4;
    int bp = (t & 15) * 4;

    float acc[4][4] = {};

    for (int k0 = 0; k0 < 256; k0 += 16) {
        int o = mTile * 64 + lo;
        float4 w4 = *(const float4*)(Wp + o * 256 + k0 + lc);
        As[lc + 0][lo] = w4.x;
        As[lc + 1][lo] = w4.y;
        As[lc + 2][lo] = w4.z;
        As[lc + 3][lo] = w4.w;
        int c = k0 + bc;
        *(float4*)&Bs[bc][bp] =
            *(const float4*)(oattn + ((size_t)(n * 256 + c)) * NPOS + pBase + bp);
        __syncthreads();
        #pragma unroll
        for (int kk = 0; kk < 16; ++kk) {
            float4 av = *(const float4*)&As[kk][ty * 4];
            float4 b4 = *(const float4*)&Bs[kk][tx * 4];
            float a[4] = {av.x, av.y, av.z, av.w};
            float bb[4] = {b4.x, b4.y, b4.z, b4.w};
            #pragma unroll
            for (int i = 0; i < 4; ++i)
                #pragma unroll
                for (int j = 0; j < 4; ++j)
                    acc[i][j] += a[i] * bb[j];
        }
        __syncthreads();
    }

    #pragma unroll
    for (int i = 0; i < 4; ++i) {
        int o = mTile * 64 + ty * 4 + i;
        float bias = bpv[o];
        *(float4*)(proj + ((size_t)(n * 256 + o)) * NPOS + pBase + tx * 4) =
            make_float4(acc[i][0] + bias, acc[i][1] + bias,
                        acc[i][2] + bias, acc[i][3] + bias);
    }
}

// ---------------------------------------------------------------------------
// Kernel 6: bilinear 48->96 upsample + residual
// ---------------------------------------------------------------------------
__global__ __launch_bounds__(256) void resize_kernel(
    const float* __restrict__ proj, const float* __restrict__ x,
    const float* __restrict__ gamma, float* __restrict__ out)
{
    int idx = blockIdx.x * 256 + threadIdx.x;
    int J = idx % 96;
    int tmp = idx / 96;
    int I = tmp % 96;
    int nc = tmp / 96;

    int jr = I >> 1;
    int r0, r1; float w0, w1;
    if ((I & 1) == 0) { r0 = (jr > 0) ? jr - 1 : 0; r1 = jr; w0 = 0.25f; w1 = 0.75f; }
    else              { r0 = jr; r1 = (jr < 47) ? jr + 1 : 47; w0 = 0.75f; w1 = 0.25f; }
    int jc = J >> 1;
    int c0, c1; float u0, u1;
    if ((J & 1) == 0) { c0 = (jc > 0) ? jc - 1 : 0; c1 = jc; u0 = 0.25f; u1 = 0.75f; }
    else              { c0 = jc; c1 = (jc < 47) ? jc + 1 : 47; u0 = 0.75f; u1 = 0.25f; }

    const float* P = proj + (size_t)nc * NPOS;
    float v = w0 * (u0 * P[r0 * 48 + c0] + u1 * P[r0 * 48 + c1]) +
              w1 * (u0 * P[r1 * 48 + c0] + u1 * P[r1 * 48 + c1]);
    out[idx] = gamma[0] * v + x[idx];
}

// ---------------------------------------------------------------------------
extern "C" void kernel_launch(void* const* d_in, const int* in_sizes, int n_in,
                              void* d_out, int out_size, void* d_ws, size_t ws_size,
                              hipStream_t stream)
{
    const float* x     = (const float*)d_in[0];
    const float* Wq    = (const float*)d_in[1];
    const float* Wk    = (const float*)d_in[2];
    const float* Wv    = (const float*)d_in[3];
    const float* Wx    = (const float*)d_in[4];
    const float* Wy    = (const float*)d_in[5];
    const float* ab    = (const float*)d_in[6];
    const float* Wp    = (const float*)d_in[7];
    const float* bp    = (const float*)d_in[8];
    const float* gamma = (const float*)d_in[9];
    float* out = (float*)d_out;

    float* ws = (float*)d_ws;
    float* posx  = ws;                               // 95*256
    float* posy  = posx + 95 * 256;                  // 95*256
    float* wkeff = posy + 95 * 256;                  // 8*256
    float* qbuf  = wkeff + 8 * 256;                  // 2*8*2304*32  [ng][p][32]
    float* vbuf  = qbuf + 2 * 8 * NPOS * 32;         // 2*8*2304*32  [n][256][p]
    float* ekA   = vbuf + 2 * 8 * NPOS * 32;         // 2*8*2304
    float* oattn = ekA + 2 * 8 * NPOS;               // 2*256*2304
    float* proj  = oattn + 2 * 256 * NPOS;           // 2*256*2304

    hipLaunchKernelGGL(pos_tables_kernel, dim3(103), dim3(256), 0, stream,
                       Wx, Wy, Wk, ab, posx, posy, wkeff);
    hipLaunchKernelGGL(qkv_kernel, dim3(9, 72), dim3(256), 0, stream,
                       x, Wq, Wv, wkeff, qbuf, vbuf, ekA);
    hipLaunchKernelGGL(softA_kernel, dim3(16), dim3(256), 0, stream, ekA);
    hipLaunchKernelGGL(attn_kernel, dim3(576), dim3(256), 0, stream,
                       qbuf, vbuf, ekA, posx, posy, oattn);
    hipLaunchKernelGGL(proj_kernel, dim3(4, 72), dim3(256), 0, stream,
                       oattn, Wp, bp, proj);
    hipLaunchKernelGGL(resize_kernel, dim3((2 * 256 * 96 * 96) / 256), dim3(256), 0, stream,
                       proj, x, gamma, out);
}